// Round 15
// baseline (174.005 us; speedup 1.0000x reference)
//
#include <hip/hip_runtime.h>
#include <hip/hip_cooperative_groups.h>
#include <hip/hip_bf16.h>
#include <math.h>

namespace cg = cooperative_groups;

// Problem constants
#define MM 2048   // context length
#define NN 256    // entities
#define LL 128    // query length
#define DD 300    // d2
#define D2 600    // 2*D
#define D4 1200   // 4*D
#define DROOT 17.320508075688775f

// GEMM geometry (gates = X @ Wsel^T), bf16 MFMA
#define KP 608    // K = 600 padded to 608 (19 * 32)
#define NP 960    // 3 gate sections (i|g|o) x 320 padded rows
#define GM 64
#define GDT 64    // d-tile
#define GK 32

typedef __attribute__((ext_vector_type(8))) short bf16x8;
typedef __attribute__((ext_vector_type(4))) float f32x4;

__device__ __forceinline__ float sigmoidf_(float x) { return 1.f / (1.f + expf(-x)); }

__device__ __forceinline__ ushort f2bf(float v) {
    union { float f; unsigned u; } x; x.f = v;
    unsigned r = x.u + 0x7fffu + ((x.u >> 16) & 1u);   // round-nearest-even
    return (ushort)(r >> 16);
}

__device__ __forceinline__ float dot4_(float4 a, float4 b) {
    return a.x * b.x + a.y * b.y + a.z * b.z + a.w * b.w;
}

// 8 bf16 (packed in uint4) dotted against 8 f32 (two float4), f32 accumulate
__device__ __forceinline__ float bfdot8(uint4 u, float4 x0, float4 x1) {
    union { unsigned v; float f; } a, b;
    float s = 0.f;
    a.v = u.x << 16; b.v = u.x & 0xffff0000u; s += a.f * x0.x; s += b.f * x0.y;
    a.v = u.y << 16; b.v = u.y & 0xffff0000u; s += a.f * x0.z; s += b.f * x0.w;
    a.v = u.z << 16; b.v = u.z & 0xffff0000u; s += a.f * x1.x; s += b.f * x1.y;
    a.v = u.w << 16; b.v = u.w & 0xffff0000u; s += a.f * x1.z; s += b.f * x1.w;
    return s;
}

__device__ __forceinline__ float wave_red_sum(float v) {
    for (int off = 32; off; off >>= 1) v += __shfl_down(v, off);
    return v;   // valid on lane 0
}

// ---------------------------------------------------------------- K_A: prep mega-kernel (input-only dependencies)
__global__ __launch_bounds__(256) void k_prep(const float* __restrict__ binM,
                                              const float* __restrict__ Wih,
                                              const float* __restrict__ U,
                                              const float* __restrict__ Wred,
                                              const float* __restrict__ query,
                                              const float* __restrict__ V,
                                              ushort* __restrict__ Wb,
                                              ushort* __restrict__ Ub,
                                              ushort* __restrict__ Wredb,
                                              unsigned* __restrict__ binMbits,
                                              float* __restrict__ qVp) {
    __shared__ float qp2[2][75];
    __shared__ float qp_s[75];
    int r = blockIdx.x, t = threadIdx.x;
    if (r < 12) {
        // ---- qV partial: block q = (kb, sl); qVp[sl][k] = sum_{d in slice} qp[d]*V[d][k]
        int kb = r >> 2, sl = r & 3;
        int dbase = sl * 75;
        if (t < 150) {
            int dd = t % 75, half = t / 75;
            float s = 0.f;
            #pragma unroll 8
            for (int l = half * 64; l < half * 64 + 64; ++l) s += query[l * DD + dbase + dd];
            qp2[half][dd] = s;
        }
        __syncthreads();
        if (t < 75) qp_s[t] = (qp2[0][t] + qp2[1][t]) * (1.f / LL);
        __syncthreads();
        int k = kb * 256 + t;
        if (k < D2) {
            float acc = 0.f;
            #pragma unroll 5
            for (int i = 0; i < 75; ++i) acc += qp_s[i] * V[(size_t)(dbase + i) * D2 + k];
            qVp[sl * D2 + k] = acc;
        }
    } else if (r < 76) {
        // ---- binM bit-pack: block handles 32 rows, thread t = column n (coalesced row reads)
        int blk = r - 12;                           // 0..63
        int m0 = blk * 32;
        unsigned mask = 0u;
        #pragma unroll 8
        for (int i = 0; i < 32; ++i) {
            if (binM[(size_t)(m0 + i) * NN + t] != 0.f) mask |= (1u << i);
        }
        binMbits[(size_t)t * 64 + blk] = mask;
    } else if (r < 76 + NP) {
        int rr = r - 76;
        int s = rr / 320, dd = rr % 320;
        bool valid = (dd < DD);
        int src = (s == 0) ? dd : ((s == 1) ? 600 + dd : 900 + dd);
        for (int e = t; e < KP; e += 256) {
            float v = (valid && e < D2) ? Wih[(size_t)src * D2 + e] : 0.f;
            Wb[(size_t)rr * KP + e] = f2bf(v);
        }
    } else if (r < 76 + NP + DD) {
        int rr = r - 76 - NP;
        for (int e = t; e < D2; e += 256) Ub[(size_t)rr * D2 + e] = f2bf(U[(size_t)rr * D2 + e]);
    } else {
        int rr = r - 76 - NP - DD;
        for (int e = t; e < D4; e += 256) Wredb[(size_t)rr * D4 + e] = f2bf(Wred[(size_t)rr * D4 + e]);
    }
}

// ---------------------------------------------------------------- K_MID: cooperative {hidden | row-stats | Et}, grid 256 x 960
// Each stage already had grid 256 = CU count -> zero occupancy loss from fusion.
__global__ __launch_bounds__(960) void k_mid(const float* __restrict__ ctx,
                                             const unsigned* __restrict__ binMbits,
                                             const float* __restrict__ qVp,
                                             const ushort* __restrict__ Ub,
                                             const float* __restrict__ adj,
                                             const float* __restrict__ bvec,
                                             const float* __restrict__ W,
                                             const float* __restrict__ w_att,
                                             const float* __restrict__ b_att,
                                             float* __restrict__ hidden,
                                             float* __restrict__ a_i,
                                             float* __restrict__ c_j,
                                             float* __restrict__ mstat,
                                             float* __restrict__ rinv,
                                             float* __restrict__ Et,
                                             float* __restrict__ EtT,
                                             float* __restrict__ ce) {
    cg::grid_group grid = cg::this_grid();
    __shared__ int lst[MM];                 // 8 KB worst-case member list
    __shared__ int wbase_s[65];
    __shared__ alignas(16) float e_s[D2];
    __shared__ float h_s[DD];
    __shared__ float red[2][16];
    __shared__ float scal[2];
    __shared__ float w_s[NN];
    __shared__ float epart[3][DD];
    int bid = blockIdx.x, t = threadIdx.x, wv = t >> 6, lane = t & 63;

    // ================= P1: hidden (+tok2ent +gamma) ; a_i ; c_j   (unit n = bid)
    {
        int n = bid;
        unsigned mword = (t < 64) ? binMbits[(size_t)n * 64 + t] : 0u;
        if (t < 64) wbase_s[t] = (int)__popc(mword);
        __syncthreads();
        if (t == 0) {
            int s = 0;
            for (int w = 0; w < 64; ++w) { int c = wbase_s[w]; wbase_s[w] = s; s += c; }
            wbase_s[64] = s;
        }
        __syncthreads();
        if (t < 64) {
            int base = wbase_s[t];
            unsigned x = mword;
            while (x) {
                int b = __ffs((int)x) - 1;
                lst[base++] = t * 32 + b;
                x &= x - 1;
            }
        }
        __syncthreads();
        int total = wbase_s[64];
        if (t < DD) {
            float sum = 0.f, mx = 0.f;      // max includes zeros of non-members
            int i = 0;
            for (; i + 4 <= total; i += 4) {
                float v0 = ctx[(size_t)lst[i] * DD + t];
                float v1 = ctx[(size_t)lst[i + 1] * DD + t];
                float v2 = ctx[(size_t)lst[i + 2] * DD + t];
                float v3 = ctx[(size_t)lst[i + 3] * DD + t];
                sum += v0; mx = fmaxf(mx, v0);
                sum += v1; mx = fmaxf(mx, v1);
                sum += v2; mx = fmaxf(mx, v2);
                sum += v3; mx = fmaxf(mx, v3);
            }
            for (; i < total; ++i) {
                float v = ctx[(size_t)lst[i] * DD + t];
                sum += v; mx = fmaxf(mx, v);
            }
            e_s[t]      = sum * (1.f / MM);
            e_s[DD + t] = mx;
        }
        __syncthreads();
        float part = 0.f;
        if (t < D2) part = e_s[t] * (qVp[t] + qVp[D2 + t] + qVp[2 * D2 + t] + qVp[3 * D2 + t]);
        part = wave_red_sum(part);
        if (lane == 0) red[0][wv] = part;
        __syncthreads();
        if (t == 0) {
            float s = 0.f;
            for (int w = 0; w < 15; ++w) s += red[0][w];
            scal[0] = sigmoidf_(s / DROOT);
        }
        __syncthreads();
        float sg = scal[0];
        const float4* e4 = (const float4*)e_s;      // 150 float4
        float4 ex0 = e4[2 * lane], ex1 = e4[2 * lane + 1];
        float4 ex2 = {0.f, 0.f, 0.f, 0.f}, ex3 = {0.f, 0.f, 0.f, 0.f};
        if (lane < 11) { ex2 = e4[128 + 2 * lane]; ex3 = e4[129 + 2 * lane]; }
        #pragma unroll 4
        for (int i = 0; i < 20; ++i) {
            int d = wv * 20 + i;                    // 15 waves * 20 = 300
            const uint4* u4 = (const uint4*)(Ub + (size_t)d * D2);   // 75 uint4 per row
            float p2 = bfdot8(u4[lane], ex0, ex1);
            if (lane < 11) p2 += bfdot8(u4[64 + lane], ex2, ex3);
            p2 = wave_red_sum(p2);
            if (lane == 0) {
                float h = sg * p2 + bvec[d];
                h_s[d] = h;
                hidden[n * DD + d] = h;
            }
        }
        __syncthreads();
        float wa = 0.f, wc = 0.f;
        if (t < DD) { float h = h_s[t]; wa = h * W[t]; wc = h * W[DD + t]; }
        wa = wave_red_sum(wa); wc = wave_red_sum(wc);
        if (lane == 0) { red[0][wv] = wa; red[1][wv] = wc; }
        __syncthreads();
        if (t == 0) {
            float A = 0.f, C = 0.f;
            for (int w = 0; w < 15; ++w) { A += red[0][w]; C += red[1][w]; }
            a_i[n] = A; c_j[n] = C;
        }
    }
    grid.sync();

    // ================= P2: softmax row stats for row j = bid (t < 256 active)
    {
        int j = bid;
        bool act = (t < NN);
        float beta = 0.f;
        if (act && adj[(size_t)j * NN + t] > 0.f) {
            float v = a_i[j] + c_j[t];
            beta = (v > 0.f) ? v : 0.01f * v;
        }
        float bm = act ? beta : -1e30f;
        for (int off = 32; off; off >>= 1) bm = fmaxf(bm, __shfl_down(bm, off));
        if (lane == 0) red[0][wv] = bm;
        __syncthreads();
        if (t == 0) {
            float m = red[0][0];
            for (int w = 1; w < 4; ++w) m = fmaxf(m, red[0][w]);
            scal[0] = m;
        }
        __syncthreads();
        float e = act ? expf(beta - scal[0]) : 0.f;
        float s1 = wave_red_sum(e);
        if (lane == 0) red[1][wv] = s1;
        __syncthreads();
        if (t == 0) {
            float s = red[1][0] + red[1][1] + red[1][2] + red[1][3];
            mstat[j] = scal[0];
            rinv[j] = 1.f / s;
        }
    }
    grid.sync();

    // ================= P3: E_t (+EtT +ce), alphas recomputed on the fly (unit i = bid)
    {
        int i = bid;
        if (t < NN) {
            float aj  = adj[(size_t)i * NN + t];
            float adT = adj[(size_t)t * NN + i];
            float v = a_i[t] + c_j[i];
            float beta = (adT > 0.f) ? ((v > 0.f) ? v : 0.01f * v) : 0.f;
            w_s[t] = aj * expf(beta - mstat[t]) * rinv[t];
        }
        __syncthreads();
        int d = t % 320, sl = t / 320;
        if (d < DD) {
            int j0 = sl * 86, j1 = (sl == 2) ? NN : (j0 + 86);
            float acc = 0.f;
            #pragma unroll 2
            for (int j = j0; j < j1; ++j) acc += w_s[j] * hidden[(size_t)j * DD + d];
            epart[sl][d] = acc;
        }
        __syncthreads();
        float pv = 0.f;
        if (t < DD) {
            float etv = fmaxf(epart[0][t] + epart[1][t] + epart[2][t], 0.f);
            Et[i * DD + t] = etv;
            EtT[(size_t)t * NN + i] = etv;
            pv = etv * w_att[DD + t];
        }
        pv = wave_red_sum(pv);
        if (lane == 0) red[0][wv] = pv;
        __syncthreads();
        if (t == 0) {
            float s = 0.f;
            for (int w = 0; w < 15; ++w) s += red[0][w];
            ce[i] = s + b_att[1];
        }
    }
}

// ---------------------------------------------------------------- K_B: fused {xbuf x4 rows | Sc2q rows}  [1024 thr]
__global__ __launch_bounds__(1024) void k_Bmid(const float* __restrict__ query,
                                               const float* __restrict__ Et,
                                               const float* __restrict__ EtT,
                                               const float* __restrict__ w_att,
                                               const float* __restrict__ b_att,
                                               const float* __restrict__ ce,
                                               const float* __restrict__ ctx,
                                               const float* __restrict__ binM,
                                               float* __restrict__ rowmax,
                                               float* __restrict__ c2qg,
                                               ushort* __restrict__ Xb) {
    __shared__ alignas(16) float qw[DD];
    __shared__ float s_row[NN];
    __shared__ alignas(16) float p_s[NN];
    __shared__ float red[16];
    __shared__ float cql_s, rmax_s, invs;
    __shared__ int lst4[4][NN];
    __shared__ int wcnt4[4][4];
    __shared__ int tot4[4];
    int t = threadIdx.x, wv = t >> 6, lane = t & 63;
    if (blockIdx.x < MM / 4) {
        // ---- xbuf: 4 context rows per block (group g handles row m)
        int g = t >> 8, tt = t & 255;
        int w2 = tt >> 6;                           // wave within group
        int m = blockIdx.x * 4 + g;
        float b = binM[(size_t)m * NN + tt];
        unsigned long long mask = __ballot(b != 0.f);
        int prefix = __popcll(mask & ((1ull << lane) - 1ull));
        if (lane == 0) wcnt4[g][w2] = (int)__popcll(mask);
        __syncthreads();
        int wbase = 0;
        for (int w = 0; w < w2; ++w) wbase += wcnt4[g][w];
        if (b != 0.f) lst4[g][wbase + prefix] = tt;
        if (tt == 0) tot4[g] = wcnt4[g][0] + wcnt4[g][1] + wcnt4[g][2] + wcnt4[g][3];
        __syncthreads();
        int total = tot4[g];
        if (tt < 8) Xb[(size_t)m * KP + D2 + tt] = 0;   // K padding
        for (int d = tt; d < DD; d += 256) {
            Xb[(size_t)m * KP + d] = f2bf(ctx[(size_t)m * DD + d]);
            float s = 0.f;
            for (int i = 0; i < total; ++i) s += Et[(size_t)lst4[g][i] * DD + d];
            Xb[(size_t)m * KP + DD + d] = f2bf(s);
        }
    } else {
        int l = blockIdx.x - MM / 4;
        float part = 0.f;
        if (t < DD) {
            float qv = query[l * DD + t];
            qw[t] = qv * w_att[2 * DD + t];
            part = qv * w_att[t];
        }
        part = wave_red_sum(part);
        if (lane == 0) red[wv] = part;
        __syncthreads();
        if (t == 0) {
            float s = 0.f;
            for (int w = 0; w < 16; ++w) s += red[w];
            cql_s = s + b_att[0];
        }
        __syncthreads();
        const float4* q4 = (const float4*)qw;       // 75 float4
        float4 qb0 = q4[lane];
        float4 qb1 = (lane < 11) ? q4[64 + lane] : float4{0.f, 0.f, 0.f, 0.f};
        float wmax = -1e30f;
        #pragma unroll 4
        for (int i = 0; i < 16; ++i) {
            int n = wv * 16 + i;                    // 16 waves * 16 = 256
            const float4* e4 = (const float4*)(Et + (size_t)n * DD);
            float4 a0 = e4[lane];
            float p2 = dot4_(a0, qb0);
            if (lane < 11) { float4 a1 = e4[64 + lane]; p2 += dot4_(a1, qb1); }
            p2 = wave_red_sum(p2);
            if (lane == 0) {
                float val = cql_s + ce[n] + p2 + b_att[2];
                s_row[n] = val;
                wmax = fmaxf(wmax, val);
            }
        }
        if (lane == 0) red[wv] = wmax;
        __syncthreads();
        if (t == 0) {
            float m = red[0];
            for (int w = 1; w < 16; ++w) m = fmaxf(m, red[w]);
            rmax_s = m;
            rowmax[l] = m;
        }
        __syncthreads();
        float e = 0.f;
        if (t < NN) e = expf(s_row[t] - rmax_s);
        float v = wave_red_sum(e);
        if (lane == 0) red[wv] = v;
        __syncthreads();
        if (t == 0) {
            float s = 0.f;
            for (int w = 0; w < 16; ++w) s += red[w];
            invs = 1.f / s;
        }
        __syncthreads();
        if (t < NN) p_s[t] = e * invs;
        __syncthreads();
        if (wv < 15) {
            const float4* p4 = (const float4*)p_s;
            float4 pb = p4[lane];
            #pragma unroll 4
            for (int i = 0; i < 20; ++i) {
                int d = wv * 20 + i;                // 15 * 20 = 300
                float4 a = ((const float4*)(EtT + (size_t)d * NN))[lane];
                float p2 = wave_red_sum(dot4_(a, pb));
                if (lane == 0) c2qg[l * DD + d] = p2;
            }
        }
    }
}

// ---------------------------------------------------------------- K_C: fused {gates GEMM + LSTM | outq (q2c inline)}  [320 thr]
__global__ __launch_bounds__(320) void k_tail(const float* __restrict__ c2qg,
                                              const float* __restrict__ rowmax,
                                              const float* __restrict__ query,
                                              const ushort* __restrict__ Wredb,
                                              const float* __restrict__ bred,
                                              const ushort* __restrict__ Xb,
                                              const ushort* __restrict__ Wb,
                                              const float* __restrict__ bih,
                                              const float* __restrict__ bhh,
                                              float* __restrict__ outq,
                                              float* __restrict__ outc) {
    __shared__ float pq[LL];
    __shared__ float q2c_s[DD];
    __shared__ alignas(16) float xs[D4];
    __shared__ float red[5];
    __shared__ float bc2[2];
    __shared__ ushort As[GM * GK];
    __shared__ ushort Bs[3][GDT * GK];
    int t = threadIdx.x, wv = t >> 6, lane = t & 63;
    if (blockIdx.x < 160) {
        // ---- gates GEMM + LSTM epilogue (256 active threads; wave 4 idles through barriers)
        int g = blockIdx.x;
        int m0 = (g & 31) * GM, d0 = (g >> 5) * GDT;
        int tid = t;
        int wm = wv >> 1, wn = wv & 1;
        int l15 = lane & 15, l4 = lane >> 4;
        f32x4 acc[3][2][2] = {};
        int srow = tid >> 2, kslot = tid & 3;
        int sidx = srow * GK + ((kslot ^ ((srow >> 1) & 3)) << 3);
        for (int k0 = 0; k0 < KP; k0 += GK) {
            if (tid < 256) {
                uint4 va = *(const uint4*)(Xb + (size_t)(m0 + srow) * KP + k0 + kslot * 8);
                *(uint4*)(As + sidx) = va;
                #pragma unroll
                for (int s = 0; s < 3; ++s) {
                    uint4 vb = *(const uint4*)(Wb + (size_t)(s * 320 + d0 + srow) * KP + k0 + kslot * 8);
                    *(uint4*)(Bs[s] + sidx) = vb;
                }
            }
            __syncthreads();
            if (tid < 256) {
                bf16x8 af[2], bfr[3][2];
                #pragma unroll
                for (int mi = 0; mi < 2; ++mi) {
                    int row = wm * 32 + mi * 16 + l15;
                    af[mi] = *(const bf16x8*)(As + row * GK + ((l4 ^ ((row >> 1) & 3)) << 3));
                }
                #pragma unroll
                for (int s = 0; s < 3; ++s)
                    #pragma unroll
                    for (int ni = 0; ni < 2; ++ni) {
                        int row = wn * 32 + ni * 16 + l15;
                        bfr[s][ni] = *(const bf16x8*)(Bs[s] + row * GK + ((l4 ^ ((row >> 1) & 3)) << 3));
                    }
                #pragma unroll
                for (int s = 0; s < 3; ++s)
                    #pragma unroll
                    for (int mi = 0; mi < 2; ++mi)
                        #pragma unroll
                        for (int ni = 0; ni < 2; ++ni)
                            acc[s][mi][ni] = __builtin_amdgcn_mfma_f32_16x16x32_bf16(af[mi], bfr[s][ni], acc[s][mi][ni], 0, 0, 0);
            }
            __syncthreads();
        }
        if (tid < 256) {
            // C/D mapping: col = lane&15, row = (lane>>4)*4 + reg ; LSTM epilogue in-register
            #pragma unroll
            for (int mi = 0; mi < 2; ++mi) {
                #pragma unroll
                for (int ni = 0; ni < 2; ++ni) {
                    int d = d0 + wn * 32 + ni * 16 + l15;
                    if (d < DD) {
                        float bi = bih[d] + bhh[d];
                        float bg = bih[2 * DD + d] + bhh[2 * DD + d];
                        float bo = bih[3 * DD + d] + bhh[3 * DD + d];
                        int mrow = m0 + wm * 32 + mi * 16 + l4 * 4;
                        #pragma unroll
                        for (int r2 = 0; r2 < 4; ++r2) {
                            float gi = acc[0][mi][ni][r2] + bi;
                            float gg = acc[1][mi][ni][r2] + bg;
                            float go = acc[2][mi][ni][r2] + bo;
                            float c = sigmoidf_(gi) * tanhf(gg);
                            outc[(size_t)(mrow + r2) * DD + d] = sigmoidf_(go) * tanhf(c);
                        }
                    }
                }
            }
        }
    } else {
        int idx = blockIdx.x - 160;
        int s = idx / LL, l = idx % LL;
        // inline q2c: softmax(rowmax) @ query
        float v = (t < LL) ? rowmax[t] : -1e30f;
        float wm = v;
        for (int off = 32; off; off >>= 1) wm = fmaxf(wm, __shfl_down(wm, off));
        if (lane == 0) red[wv] = wm;
        __syncthreads();
        if (t == 0) {
            float m = red[0];
            for (int w = 1; w < 5; ++w) m = fmaxf(m, red[w]);
            bc2[0] = m;
        }
        __syncthreads();
        float e = (t < LL) ? expf(v - bc2[0]) : 0.f;
        float ws_ = wave_red_sum(e);
        __syncthreads();
        if (lane == 0) red[wv] = ws_;
        __syncthreads();
        if (t == 0) {
            float sm = 0.f;
            for (int w = 0; w < 5; ++w) sm += red[w];
            bc2[1] = 1.f / sm;
        }
        __syncthreads();
        if (t < LL) pq[t] = e * bc2[1];
        __syncthreads();
        if (t < DD) {
            float s2 = 0.f;
            #pragma unroll 4
            for (int l2 = 0; l2 < LL; ++l2) s2 += pq[l2] * query[l2 * DD + t];
            q2c_s[t] = s2;
        }
        __syncthreads();
        if (t < DD) {
            float c = c2qg[l * DD + t];
            float qv = query[l * DD + t];
            xs[t] = qv; xs[DD + t] = c; xs[2 * DD + t] = qv * c; xs[3 * DD + t] = qv * q2c_s[t];
        }
        __syncthreads();
        const float4* x4 = (const float4*)xs;       // 300 float4
        float4 xb0 = x4[2 * lane], xb1 = x4[2 * lane + 1];
        float4 xb2 = x4[128 + 2 * lane], xb3 = x4[129 + 2 * lane];
        float4 xb4 = {0.f, 0.f, 0.f, 0.f}, xb5 = {0.f, 0.f, 0.f, 0.f};
        if (lane < 22) { xb4 = x4[256 + 2 * lane]; xb5 = x4[257 + 2 * lane]; }
        int d0 = s * 100 + wv * 20;                 // 3 slices * 5 waves * 20 = 300
        #pragma unroll 2
        for (int i = 0; i < 20; ++i) {
            int d = d0 + i;
            const uint4* w4 = (const uint4*)(Wredb + (size_t)d * D4);   // 150 uint4 per row
            float p2 = bfdot8(w4[lane], xb0, xb1) + bfdot8(w4[64 + lane], xb2, xb3);
            if (lane < 22) p2 += bfdot8(w4[128 + lane], xb4, xb5);
            p2 = wave_red_sum(p2);
            if (lane == 0) outq[l * DD + d] = bred[d] + p2;
        }
    }
}

// ================================================================ launch
extern "C" void kernel_launch(void* const* d_in, const int* in_sizes, int n_in,
                              void* d_out, int out_size, void* d_ws, size_t ws_size,
                              hipStream_t stream) {
    const float* context = (const float*)d_in[0];
    const float* query   = (const float*)d_in[1];
    const float* binM    = (const float*)d_in[2];
    const float* adj     = (const float*)d_in[3];
    const float* V       = (const float*)d_in[4];
    const float* U       = (const float*)d_in[5];
    const float* bvec    = (const float*)d_in[6];
    const float* W       = (const float*)d_in[7];
    const float* w_att   = (const float*)d_in[8];
    const float* b_att   = (const float*)d_in[9];
    const float* W_red   = (const float*)d_in[10];
    const float* b_red   = (const float*)d_in[11];
    const float* W_ih    = (const float*)d_in[12];
    const float* b_ih    = (const float*)d_in[13];
    const float* b_hh    = (const float*)d_in[14];

    float* ws = (float*)d_ws;
    float* qVp    = ws;                 // 2400 (4 slices x 600)
    float* hidden = qVp    + 2400;      // 76800
    float* a_i    = hidden + 76800;     // 256
    float* c_j    = a_i    + 256;       // 256
    float* mstat  = c_j    + 256;       // 256
    float* rinv   = mstat  + 256;       // 256
    float* Et     = rinv   + 256;       // 76800
    float* EtT    = Et     + 76800;     // 76800
    float* ce     = EtT    + 76800;     // 256
    float* rmax   = ce     + 256;       // 128
    float* c2qg   = rmax   + 128;       // 38400
    unsigned* binMbits = (unsigned*)(c2qg + 38400);          // 256*64 u32 = 64 KB
    ushort* Xb    = (ushort*)(binMbits + (size_t)NN * 64);   // MM*KP ushorts
    ushort* Wb    = Xb + (size_t)MM * KP;                    // NP*KP ushorts
    ushort* Ub    = Wb + (size_t)NP * KP;                    // DD*D2 ushorts
    ushort* Wredb = Ub + (size_t)DD * D2;                    // DD*D4 ushorts

    float* outc = (float*)d_out;            // ctx: (M, D)
    float* outq = (float*)d_out + MM * DD;  // qry: (L, D)

    hipLaunchKernelGGL(k_prep, dim3(76 + NP + 2 * DD), dim3(256), 0, stream,
                       binM, W_ih, U, W_red, query, V, Wb, Ub, Wredb, binMbits, qVp);

    void* args[] = {
        (void*)&context, (void*)&binMbits, (void*)&qVp, (void*)&Ub, (void*)&adj,
        (void*)&bvec, (void*)&W, (void*)&w_att, (void*)&b_att,
        (void*)&hidden, (void*)&a_i, (void*)&c_j, (void*)&mstat, (void*)&rinv,
        (void*)&Et, (void*)&EtT, (void*)&ce
    };
    hipLaunchCooperativeKernel((const void*)k_mid, dim3(NN), dim3(960), args, 0, stream);

    hipLaunchKernelGGL(k_Bmid,    dim3(MM / 4 + LL), dim3(1024), 0, stream,
                       query, Et, EtT, w_att, b_att, ce, context, binM, rmax, c2qg, Xb);
    hipLaunchKernelGGL(k_tail,    dim3(160 + 3 * LL), dim3(320), 0, stream,
                       c2qg, rmax, query, Wredb, b_red, Xb, Wb, b_ih, b_hh, outq, outc);
}

// Round 16
// 115.416 us; speedup vs baseline: 1.5076x; 1.5076x over previous
//
#include <hip/hip_runtime.h>
#include <hip/hip_bf16.h>
#include <math.h>

// Problem constants
#define MM 2048   // context length
#define NN 256    // entities
#define LL 128    // query length
#define DD 300    // d2
#define D2 600    // 2*D
#define D4 1200   // 4*D
#define DROOT 17.320508075688775f

// GEMM geometry (gates = X @ Wsel^T), bf16 MFMA
#define KP 608    // K = 600 padded to 608 (19 * 32)
#define NP 960    // 3 gate sections (i|g|o) x 320 padded rows
#define GM 64
#define GDT 64    // d-tile
#define GK 32

typedef __attribute__((ext_vector_type(8))) short bf16x8;
typedef __attribute__((ext_vector_type(4))) float f32x4;

__device__ __forceinline__ float sigmoidf_(float x) { return 1.f / (1.f + expf(-x)); }

__device__ __forceinline__ ushort f2bf(float v) {
    union { float f; unsigned u; } x; x.f = v;
    unsigned r = x.u + 0x7fffu + ((x.u >> 16) & 1u);   // round-nearest-even
    return (ushort)(r >> 16);
}

__device__ __forceinline__ float dot4_(float4 a, float4 b) {
    return a.x * b.x + a.y * b.y + a.z * b.z + a.w * b.w;
}

// 8 bf16 (packed in uint4) dotted against 8 f32 (two float4), f32 accumulate
__device__ __forceinline__ float bfdot8(uint4 u, float4 x0, float4 x1) {
    union { unsigned v; float f; } a, b;
    float s = 0.f;
    a.v = u.x << 16; b.v = u.x & 0xffff0000u; s += a.f * x0.x; s += b.f * x0.y;
    a.v = u.y << 16; b.v = u.y & 0xffff0000u; s += a.f * x0.z; s += b.f * x0.w;
    a.v = u.z << 16; b.v = u.z & 0xffff0000u; s += a.f * x1.x; s += b.f * x1.y;
    a.v = u.w << 16; b.v = u.w & 0xffff0000u; s += a.f * x1.z; s += b.f * x1.w;
    return s;
}

__device__ __forceinline__ float wave_red_sum(float v) {
    for (int off = 32; off; off >>= 1) v += __shfl_down(v, off);
    return v;   // valid on lane 0
}

// ---------------------------------------------------------------- K_A: prep mega-kernel (input-only dependencies)
// blocks [0, NP):                 Wb rows (W_ih i|g|o sections, bf16, K padded)
// blocks [NP, NP+DD):             Ub rows
// blocks [NP+DD, NP+2DD):         Wredb rows
// blocks [NP+2DD, +12):           qV partials (3 k-blocks x 4 d-slices, chain 75)
// blocks [NP+2DD+12, +64):        binM bit-pack u32 (32 rows each, chain 32)
__global__ __launch_bounds__(256) void k_prep(const float* __restrict__ binM,
                                              const float* __restrict__ Wih,
                                              const float* __restrict__ U,
                                              const float* __restrict__ Wred,
                                              const float* __restrict__ query,
                                              const float* __restrict__ V,
                                              ushort* __restrict__ Wb,
                                              ushort* __restrict__ Ub,
                                              ushort* __restrict__ Wredb,
                                              unsigned* __restrict__ binMbits,
                                              float* __restrict__ qVp) {
    __shared__ float qp2[2][75];
    __shared__ float qp_s[75];
    int r = blockIdx.x, t = threadIdx.x;
    if (r < NP) {
        int s = r / 320, dd = r % 320;
        bool valid = (dd < DD);
        int src = (s == 0) ? dd : ((s == 1) ? 600 + dd : 900 + dd);
        for (int e = t; e < KP; e += 256) {
            float v = (valid && e < D2) ? Wih[(size_t)src * D2 + e] : 0.f;
            Wb[(size_t)r * KP + e] = f2bf(v);
        }
    } else if (r < NP + DD) {
        int rr = r - NP;
        for (int e = t; e < D2; e += 256) Ub[(size_t)rr * D2 + e] = f2bf(U[(size_t)rr * D2 + e]);
    } else if (r < NP + 2 * DD) {
        int rr = r - NP - DD;
        for (int e = t; e < D4; e += 256) Wredb[(size_t)rr * D4 + e] = f2bf(Wred[(size_t)rr * D4 + e]);
    } else if (r < NP + 2 * DD + 12) {
        // ---- qV partial: block q = (kb, sl); qVp[sl][k] = sum_{d in slice} qp[d]*V[d][k]
        int q = r - NP - 2 * DD;
        int kb = q >> 2, sl = q & 3;
        int dbase = sl * 75;
        // mean-pool slice: two 64-long half-sums per d (chain 64)
        if (t < 150) {
            int dd = t % 75, half = t / 75;
            float s = 0.f;
            #pragma unroll 8
            for (int l = half * 64; l < half * 64 + 64; ++l) s += query[l * DD + dbase + dd];
            qp2[half][dd] = s;
        }
        __syncthreads();
        if (t < 75) qp_s[t] = (qp2[0][t] + qp2[1][t]) * (1.f / LL);
        __syncthreads();
        int k = kb * 256 + t;
        if (k < D2) {
            float acc = 0.f;
            #pragma unroll 5
            for (int i = 0; i < 75; ++i) acc += qp_s[i] * V[(size_t)(dbase + i) * D2 + k];
            qVp[sl * D2 + k] = acc;
        }
    } else {
        // ---- binM bit-pack: block handles 32 rows, thread t = column n (coalesced row reads)
        int blk = r - NP - 2 * DD - 12;             // 0..63
        int m0 = blk * 32;
        unsigned mask = 0u;
        #pragma unroll 8
        for (int i = 0; i < 32; ++i) {
            if (binM[(size_t)(m0 + i) * NN + t] != 0.f) mask |= (1u << i);
        }
        binMbits[(size_t)t * 64 + blk] = mask;
    }
}

// ---------------------------------------------------------------- K3: hidden (+tok2ent +gamma fused) ; a_i ; c_j
__global__ __launch_bounds__(960) void k_hidden(const float* __restrict__ ctx,
                                                const unsigned* __restrict__ binMbits,
                                                const float* __restrict__ qVp,
                                                const ushort* __restrict__ Ub,
                                                const float* __restrict__ bvec,
                                                const float* __restrict__ W,
                                                float* __restrict__ hidden,
                                                float* __restrict__ a_i,
                                                float* __restrict__ c_j) {
    __shared__ int lst[MM];                 // worst-case capacity (8 KB)
    __shared__ int wbase_s[65];
    __shared__ alignas(16) float e_s[D2];
    __shared__ float h_s[DD];
    __shared__ float red[2][16];
    __shared__ float sig_s;
    int n = blockIdx.x, t = threadIdx.x, wv = t >> 6, lane = t & 63;
    // ---- tok2ent: expand u32 bitmask words to member list (ascending m)
    unsigned mword = (t < 64) ? binMbits[(size_t)n * 64 + t] : 0u;
    if (t < 64) wbase_s[t] = (int)__popc(mword);
    __syncthreads();
    if (t == 0) {
        int s = 0;
        for (int w = 0; w < 64; ++w) { int c = wbase_s[w]; wbase_s[w] = s; s += c; }
        wbase_s[64] = s;
    }
    __syncthreads();
    if (t < 64) {
        int base = wbase_s[t];
        unsigned x = mword;
        while (x) {
            int b = __ffs((int)x) - 1;
            lst[base++] = t * 32 + b;
            x &= x - 1;
        }
    }
    __syncthreads();
    int total = wbase_s[64];
    // ---- accumulate member ctx rows into e_s = [mean | max]
    if (t < DD) {
        float sum = 0.f, mx = 0.f;          // max includes zeros of non-members
        int i = 0;
        for (; i + 4 <= total; i += 4) {
            float v0 = ctx[(size_t)lst[i] * DD + t];
            float v1 = ctx[(size_t)lst[i + 1] * DD + t];
            float v2 = ctx[(size_t)lst[i + 2] * DD + t];
            float v3 = ctx[(size_t)lst[i + 3] * DD + t];
            sum += v0; mx = fmaxf(mx, v0);
            sum += v1; mx = fmaxf(mx, v1);
            sum += v2; mx = fmaxf(mx, v2);
            sum += v3; mx = fmaxf(mx, v3);
        }
        for (; i < total; ++i) {
            float v = ctx[(size_t)lst[i] * DD + t];
            sum += v; mx = fmaxf(mx, v);
        }
        e_s[t]      = sum * (1.f / MM);
        e_s[DD + t] = mx;
    }
    __syncthreads();
    // ---- gamma: sigmoid(dot(qV, e_s)/sqrt(D)) ; qV = sum of 4 partial slices
    float part = 0.f;
    if (t < D2) part = e_s[t] * (qVp[t] + qVp[D2 + t] + qVp[2 * D2 + t] + qVp[3 * D2 + t]);
    part = wave_red_sum(part);
    if (lane == 0) red[0][wv] = part;
    __syncthreads();
    if (t == 0) {
        float s = 0.f;
        for (int w = 0; w < 15; ++w) s += red[0][w];
        sig_s = sigmoidf_(s / DROOT);
    }
    __syncthreads();
    float sg = sig_s;
    const float4* e4 = (const float4*)e_s;          // 150 float4 = 600 f32
    float4 ex0 = e4[2 * lane], ex1 = e4[2 * lane + 1];
    float4 ex2 = {0.f, 0.f, 0.f, 0.f}, ex3 = {0.f, 0.f, 0.f, 0.f};
    if (lane < 11) { ex2 = e4[128 + 2 * lane]; ex3 = e4[129 + 2 * lane]; }
    #pragma unroll 4
    for (int i = 0; i < 20; ++i) {
        int d = wv * 20 + i;                        // 15 waves * 20 = 300
        const uint4* u4 = (const uint4*)(Ub + (size_t)d * D2);   // 75 uint4 per row
        float p2 = bfdot8(u4[lane], ex0, ex1);
        if (lane < 11) p2 += bfdot8(u4[64 + lane], ex2, ex3);
        p2 = wave_red_sum(p2);
        if (lane == 0) {
            float h = sg * p2 + bvec[d];
            h_s[d] = h;
            hidden[n * DD + d] = h;
        }
    }
    __syncthreads();
    float wa = 0.f, wc = 0.f;
    if (t < DD) { float h = h_s[t]; wa = h * W[t]; wc = h * W[DD + t]; }
    wa = wave_red_sum(wa); wc = wave_red_sum(wc);
    if (lane == 0) { red[0][wv] = wa; red[1][wv] = wc; }
    __syncthreads();
    if (t == 0) {
        float A = 0.f, C = 0.f;
        for (int w = 0; w < 15; ++w) { A += red[0][w]; C += red[1][w]; }
        a_i[n] = A; c_j[n] = C;
    }
}

// ---------------------------------------------------------------- K4: alphas = softmax(betas, axis=1)
__global__ __launch_bounds__(256) void k_alphas(const float* __restrict__ adj,
                                                const float* __restrict__ ai,
                                                const float* __restrict__ cj,
                                                float* __restrict__ alphas) {
    __shared__ float red[4];
    __shared__ float bc[2];
    int i = blockIdx.x, j = threadIdx.x;
    float beta = 0.f;
    if (adj[i * NN + j] > 0.f) {
        float v = ai[i] + cj[j];
        beta = (v > 0.f) ? v : 0.01f * v;
    }
    float wm = beta;
    for (int off = 32; off; off >>= 1) wm = fmaxf(wm, __shfl_down(wm, off));
    if ((j & 63) == 0) red[j >> 6] = wm;
    __syncthreads();
    if (j == 0) bc[0] = fmaxf(fmaxf(red[0], red[1]), fmaxf(red[2], red[3]));
    __syncthreads();
    float e = expf(beta - bc[0]);
    float ws_ = e;
    for (int off = 32; off; off >>= 1) ws_ += __shfl_down(ws_, off);
    __syncthreads();
    if ((j & 63) == 0) red[j >> 6] = ws_;
    __syncthreads();
    if (j == 0) bc[1] = 1.f / (red[0] + red[1] + red[2] + red[3]);
    __syncthreads();
    alphas[i * NN + j] = e * bc[1];
}

// ---------------------------------------------------------------- K5: E_t (+EtT +ce fused)  [960 thr, j-sliced, lane-coalesced]
__global__ __launch_bounds__(960) void k_Et(const float* __restrict__ adj,
                                            const float* __restrict__ alphas,
                                            const float* __restrict__ hidden,
                                            const float* __restrict__ w_att,
                                            const float* __restrict__ b_att,
                                            float* __restrict__ Et,
                                            float* __restrict__ EtT,
                                            float* __restrict__ ce) {
    __shared__ float w_s[NN];
    __shared__ float epart[3][DD];
    __shared__ float red[16];
    int i = blockIdx.x, t = threadIdx.x, wv = t >> 6;
    if (t < NN) w_s[t] = adj[i * NN + t] * alphas[t * NN + i];
    __syncthreads();
    int d = t % 320, sl = t / 320;
    int j0 = sl * 86, j1 = (sl == 2) ? NN : (j0 + 86);
    if (d < DD) {
        float acc = 0.f;
        #pragma unroll 2
        for (int j = j0; j < j1; ++j) acc += w_s[j] * hidden[(size_t)j * DD + d];
        epart[sl][d] = acc;
    }
    __syncthreads();
    float pv = 0.f;
    if (t < DD) {
        float etv = fmaxf(epart[0][t] + epart[1][t] + epart[2][t], 0.f);
        Et[i * DD + t] = etv;
        EtT[(size_t)t * NN + i] = etv;
        pv = etv * w_att[DD + t];
    }
    pv = wave_red_sum(pv);
    if ((t & 63) == 0) red[wv] = pv;
    __syncthreads();
    if (t == 0) {
        float s = 0.f;
        for (int w = 0; w < 15; ++w) s += red[w];
        ce[i] = s + b_att[1];
    }
}

// ---------------------------------------------------------------- K_B: fused {Sc2q rows | xbuf x4 rows}  [1024 thr]
__global__ __launch_bounds__(1024) void k_Bmid(const float* __restrict__ query,
                                               const float* __restrict__ Et,
                                               const float* __restrict__ EtT,
                                               const float* __restrict__ w_att,
                                               const float* __restrict__ b_att,
                                               const float* __restrict__ ce,
                                               const float* __restrict__ ctx,
                                               const float* __restrict__ binM,
                                               float* __restrict__ rowmax,
                                               float* __restrict__ c2qg,
                                               ushort* __restrict__ Xb) {
    __shared__ alignas(16) float qw[DD];
    __shared__ float s_row[NN];
    __shared__ alignas(16) float p_s[NN];
    __shared__ float red[16];
    __shared__ float cql_s, rmax_s, invs;
    __shared__ int lst4[4][NN];
    __shared__ int wcnt4[4][4];
    __shared__ int tot4[4];
    int t = threadIdx.x, wv = t >> 6, lane = t & 63;
    if (blockIdx.x < LL) {
        int l = blockIdx.x;
        float part = 0.f;
        if (t < DD) {
            float qv = query[l * DD + t];
            qw[t] = qv * w_att[2 * DD + t];
            part = qv * w_att[t];
        }
        part = wave_red_sum(part);
        if (lane == 0) red[wv] = part;
        __syncthreads();
        if (t == 0) {
            float s = 0.f;
            for (int w = 0; w < 16; ++w) s += red[w];
            cql_s = s + b_att[0];
        }
        __syncthreads();
        const float4* q4 = (const float4*)qw;       // 75 float4
        float4 qb0 = q4[lane];
        float4 qb1 = (lane < 11) ? q4[64 + lane] : float4{0.f, 0.f, 0.f, 0.f};
        float wmax = -1e30f;
        #pragma unroll 4
        for (int i = 0; i < 16; ++i) {
            int n = wv * 16 + i;                    // 16 waves * 16 = 256
            const float4* e4 = (const float4*)(Et + (size_t)n * DD);
            float4 a0 = e4[lane];
            float p2 = dot4_(a0, qb0);
            if (lane < 11) { float4 a1 = e4[64 + lane]; p2 += dot4_(a1, qb1); }
            p2 = wave_red_sum(p2);
            if (lane == 0) {
                float val = cql_s + ce[n] + p2 + b_att[2];
                s_row[n] = val;
                wmax = fmaxf(wmax, val);
            }
        }
        if (lane == 0) red[wv] = wmax;
        __syncthreads();
        if (t == 0) {
            float m = red[0];
            for (int w = 1; w < 16; ++w) m = fmaxf(m, red[w]);
            rmax_s = m;
            rowmax[l] = m;
        }
        __syncthreads();
        float e = 0.f;
        if (t < NN) e = expf(s_row[t] - rmax_s);
        float v = wave_red_sum(e);
        if (lane == 0) red[wv] = v;
        __syncthreads();
        if (t == 0) {
            float s = 0.f;
            for (int w = 0; w < 16; ++w) s += red[w];
            invs = 1.f / s;
        }
        __syncthreads();
        if (t < NN) p_s[t] = e * invs;
        __syncthreads();
        if (wv < 15) {
            const float4* p4 = (const float4*)p_s;
            float4 pb = p4[lane];
            #pragma unroll 4
            for (int i = 0; i < 20; ++i) {
                int d = wv * 20 + i;                // 15 * 20 = 300
                float4 a = ((const float4*)(EtT + (size_t)d * NN))[lane];
                float p2 = wave_red_sum(dot4_(a, pb));
                if (lane == 0) c2qg[l * DD + d] = p2;
            }
        }
    } else {
        // ---- xbuf: 4 context rows per block (group g handles row m)
        int g = t >> 8, tt = t & 255;
        int w2 = tt >> 6;                           // wave within group
        int m = (blockIdx.x - LL) * 4 + g;
        float b = binM[(size_t)m * NN + tt];
        unsigned long long mask = __ballot(b != 0.f);
        int prefix = __popcll(mask & ((1ull << lane) - 1ull));
        if (lane == 0) wcnt4[g][w2] = (int)__popcll(mask);
        __syncthreads();
        int wbase = 0;
        for (int w = 0; w < w2; ++w) wbase += wcnt4[g][w];
        if (b != 0.f) lst4[g][wbase + prefix] = tt;
        if (tt == 0) tot4[g] = wcnt4[g][0] + wcnt4[g][1] + wcnt4[g][2] + wcnt4[g][3];
        __syncthreads();
        int total = tot4[g];
        if (tt < 8) Xb[(size_t)m * KP + D2 + tt] = 0;   // K padding
        for (int d = tt; d < DD; d += 256) {
            Xb[(size_t)m * KP + d] = f2bf(ctx[(size_t)m * DD + d]);
            float s = 0.f;
            for (int i = 0; i < total; ++i) s += Et[(size_t)lst4[g][i] * DD + d];
            Xb[(size_t)m * KP + DD + d] = f2bf(s);
        }
    }
}

// ---------------------------------------------------------------- K_C: fused {outq (q2c inline) | gates GEMM + LSTM}  [320 thr]
// blocks [0, 3*LL):        outq:  s = bid/LL, l = bid%LL
// blocks [3*LL, 3*LL+160): gemm:  g = bid-3*LL, m-tile = g&31, d-tile = g>>5
__global__ __launch_bounds__(320) void k_tail(const float* __restrict__ c2qg,
                                              const float* __restrict__ rowmax,
                                              const float* __restrict__ query,
                                              const ushort* __restrict__ Wredb,
                                              const float* __restrict__ bred,
                                              const ushort* __restrict__ Xb,
                                              const ushort* __restrict__ Wb,
                                              const float* __restrict__ bih,
                                              const float* __restrict__ bhh,
                                              float* __restrict__ outq,
                                              float* __restrict__ outc) {
    __shared__ float pq[LL];
    __shared__ float q2c_s[DD];
    __shared__ alignas(16) float xs[D4];
    __shared__ float red[5];
    __shared__ float bc2[2];
    __shared__ ushort As[GM * GK];
    __shared__ ushort Bs[3][GDT * GK];
    int t = threadIdx.x, wv = t >> 6, lane = t & 63;
    if (blockIdx.x < 3 * LL) {
        int s = blockIdx.x / LL, l = blockIdx.x % LL;
        // inline q2c: softmax(rowmax) @ query
        float v = (t < LL) ? rowmax[t] : -1e30f;
        float wm = v;
        for (int off = 32; off; off >>= 1) wm = fmaxf(wm, __shfl_down(wm, off));
        if (lane == 0) red[wv] = wm;
        __syncthreads();
        if (t == 0) {
            float m = red[0];
            for (int w = 1; w < 5; ++w) m = fmaxf(m, red[w]);
            bc2[0] = m;
        }
        __syncthreads();
        float e = (t < LL) ? expf(v - bc2[0]) : 0.f;
        float ws_ = wave_red_sum(e);
        __syncthreads();
        if (lane == 0) red[wv] = ws_;
        __syncthreads();
        if (t == 0) {
            float sm = 0.f;
            for (int w = 0; w < 5; ++w) sm += red[w];
            bc2[1] = 1.f / sm;
        }
        __syncthreads();
        if (t < LL) pq[t] = e * bc2[1];
        __syncthreads();
        if (t < DD) {
            float s2 = 0.f;
            #pragma unroll 4
            for (int l2 = 0; l2 < LL; ++l2) s2 += pq[l2] * query[l2 * DD + t];
            q2c_s[t] = s2;
        }
        __syncthreads();
        if (t < DD) {
            float c = c2qg[l * DD + t];
            float qv = query[l * DD + t];
            xs[t] = qv; xs[DD + t] = c; xs[2 * DD + t] = qv * c; xs[3 * DD + t] = qv * q2c_s[t];
        }
        __syncthreads();
        const float4* x4 = (const float4*)xs;       // 300 float4
        float4 xb0 = x4[2 * lane], xb1 = x4[2 * lane + 1];
        float4 xb2 = x4[128 + 2 * lane], xb3 = x4[129 + 2 * lane];
        float4 xb4 = {0.f, 0.f, 0.f, 0.f}, xb5 = {0.f, 0.f, 0.f, 0.f};
        if (lane < 22) { xb4 = x4[256 + 2 * lane]; xb5 = x4[257 + 2 * lane]; }
        int d0 = s * 100 + wv * 20;                 // 3 slices * 5 waves * 20 = 300
        #pragma unroll 2
        for (int i = 0; i < 20; ++i) {
            int d = d0 + i;
            const uint4* w4 = (const uint4*)(Wredb + (size_t)d * D4);   // 150 uint4 per row
            float p2 = bfdot8(w4[lane], xb0, xb1) + bfdot8(w4[64 + lane], xb2, xb3);
            if (lane < 22) p2 += bfdot8(w4[128 + lane], xb4, xb5);
            p2 = wave_red_sum(p2);
            if (lane == 0) outq[l * DD + d] = bred[d] + p2;
        }
    } else {
        // ---- gates GEMM + LSTM epilogue (256 active threads; wave 4 idles through barriers)
        int g = blockIdx.x - 3 * LL;
        int m0 = (g & 31) * GM, d0 = (g >> 5) * GDT;
        int tid = t;
        int wm = wv >> 1, wn = wv & 1;
        int l15 = lane & 15, l4 = lane >> 4;
        f32x4 acc[3][2][2] = {};
        int srow = tid >> 2, kslot = tid & 3;
        int sidx = srow * GK + ((kslot ^ ((srow >> 1) & 3)) << 3);
        for (int k0 = 0; k0 < KP; k0 += GK) {
            if (tid < 256) {
                uint4 va = *(const uint4*)(Xb + (size_t)(m0 + srow) * KP + k0 + kslot * 8);
                *(uint4*)(As + sidx) = va;
                #pragma unroll
                for (int s = 0; s < 3; ++s) {
                    uint4 vb = *(const uint4*)(Wb + (size_t)(s * 320 + d0 + srow) * KP + k0 + kslot * 8);
                    *(uint4*)(Bs[s] + sidx) = vb;
                }
            }
            __syncthreads();
            if (tid < 256) {
                bf16x8 af[2], bfr[3][2];
                #pragma unroll
                for (int mi = 0; mi < 2; ++mi) {
                    int row = wm * 32 + mi * 16 + l15;
                    af[mi] = *(const bf16x8*)(As + row * GK + ((l4 ^ ((row >> 1) & 3)) << 3));
                }
                #pragma unroll
                for (int s = 0; s < 3; ++s)
                    #pragma unroll
                    for (int ni = 0; ni < 2; ++ni) {
                        int row = wn * 32 + ni * 16 + l15;
                        bfr[s][ni] = *(const bf16x8*)(Bs[s] + row * GK + ((l4 ^ ((row >> 1) & 3)) << 3));
                    }
                #pragma unroll
                for (int s = 0; s < 3; ++s)
                    #pragma unroll
                    for (int mi = 0; mi < 2; ++mi)
                        #pragma unroll
                        for (int ni = 0; ni < 2; ++ni)
                            acc[s][mi][ni] = __builtin_amdgcn_mfma_f32_16x16x32_bf16(af[mi], bfr[s][ni], acc[s][mi][ni], 0, 0, 0);
            }
            __syncthreads();
        }
        if (tid < 256) {
            // C/D mapping: col = lane&15, row = (lane>>4)*4 + reg ; LSTM epilogue in-register
            #pragma unroll
            for (int mi = 0; mi < 2; ++mi) {
                #pragma unroll
                for (int ni = 0; ni < 2; ++ni) {
                    int d = d0 + wn * 32 + ni * 16 + l15;
                    if (d < DD) {
                        float bi = bih[d] + bhh[d];
                        float bg = bih[2 * DD + d] + bhh[2 * DD + d];
                        float bo = bih[3 * DD + d] + bhh[3 * DD + d];
                        int mrow = m0 + wm * 32 + mi * 16 + l4 * 4;
                        #pragma unroll
                        for (int r2 = 0; r2 < 4; ++r2) {
                            float gi = acc[0][mi][ni][r2] + bi;
                            float gg = acc[1][mi][ni][r2] + bg;
                            float go = acc[2][mi][ni][r2] + bo;
                            float c = sigmoidf_(gi) * tanhf(gg);
                            outc[(size_t)(mrow + r2) * DD + d] = sigmoidf_(go) * tanhf(c);
                        }
                    }
                }
            }
        }
    }
}

// ================================================================ launch
extern "C" void kernel_launch(void* const* d_in, const int* in_sizes, int n_in,
                              void* d_out, int out_size, void* d_ws, size_t ws_size,
                              hipStream_t stream) {
    const float* context = (const float*)d_in[0];
    const float* query   = (const float*)d_in[1];
    const float* binM    = (const float*)d_in[2];
    const float* adj     = (const float*)d_in[3];
    const float* V       = (const float*)d_in[4];
    const float* U       = (const float*)d_in[5];
    const float* bvec    = (const float*)d_in[6];
    const float* W       = (const float*)d_in[7];
    const float* w_att   = (const float*)d_in[8];
    const float* b_att   = (const float*)d_in[9];
    const float* W_red   = (const float*)d_in[10];
    const float* b_red   = (const float*)d_in[11];
    const float* W_ih    = (const float*)d_in[12];
    const float* b_ih    = (const float*)d_in[13];
    const float* b_hh    = (const float*)d_in[14];

    float* ws = (float*)d_ws;
    float* qVp    = ws;                 // 2400 (4 slices x 600)
    float* hidden = qVp    + 2400;      // 76800
    float* a_i    = hidden + 76800;     // 256
    float* c_j    = a_i    + 256;       // 256
    float* alphas = c_j    + 256;       // 65536
    float* Et     = alphas + 65536;     // 76800
    float* EtT    = Et     + 76800;     // 76800
    float* ce     = EtT    + 76800;     // 256
    float* rmax   = ce     + 256;       // 128
    float* c2qg   = rmax   + 128;       // 38400
    unsigned* binMbits = (unsigned*)(c2qg + 38400);       // 256*64 u32 = 64 KB
    ushort* Xb    = (ushort*)(binMbits + (size_t)NN * 64);   // MM*KP ushorts
    ushort* Wb    = Xb + (size_t)MM * KP;                    // NP*KP ushorts
    ushort* Ub    = Wb + (size_t)NP * KP;                    // DD*D2 ushorts
    ushort* Wredb = Ub + (size_t)DD * D2;                    // DD*D4 ushorts

    float* outc = (float*)d_out;            // ctx: (M, D)
    float* outq = (float*)d_out + MM * DD;  // qry: (L, D)

    hipLaunchKernelGGL(k_prep,    dim3(NP + 2 * DD + 12 + 64), dim3(256), 0, stream,
                       binM, W_ih, U, W_red, query, V, Wb, Ub, Wredb, binMbits, qVp);
    hipLaunchKernelGGL(k_hidden,  dim3(NN), dim3(960), 0, stream, context, binMbits, qVp, Ub, bvec, W, hidden, a_i, c_j);
    hipLaunchKernelGGL(k_alphas,  dim3(NN), dim3(256), 0, stream, adj, a_i, c_j, alphas);
    hipLaunchKernelGGL(k_Et,      dim3(NN), dim3(960), 0, stream, adj, alphas, hidden, w_att, b_att, Et, EtT, ce);
    hipLaunchKernelGGL(k_Bmid,    dim3(LL + MM / 4), dim3(1024), 0, stream,
                       query, Et, EtT, w_att, b_att, ce, context, binM, rmax, c2qg, Xb);
    hipLaunchKernelGGL(k_tail,    dim3(3 * LL + 160), dim3(320), 0, stream,
                       c2qg, rmax, query, Wredb, b_red, Xb, Wb, b_ih, b_hh, outq, outc);
}